// Round 1
// baseline (62.628 us; speedup 1.0000x reference)
//
#include <hip/hip_runtime.h>

// Problem constants (from reference): x (B,C,P) f32, inds (B,P,3) i32,
// out (B,C,H,W) f32 zero-initialized scatter target.
#define Bn 4
#define Cn 64
#define Pn 12000
#define Hn 512
#define Wn 512
#define HWn (Hn * Wn)

// Pass 1: winner[b,y,x] = max(p+1) over valid points targeting that cell.
// atomicMax over p reproduces numpy last-write-wins (within a batch, larger p
// is later in the flattened index order; across batches targets never alias).
__global__ void pp_scatter_winner(const int* __restrict__ inds,
                                  int* __restrict__ winner, int total) {
    int tid = blockIdx.x * blockDim.x + threadIdx.x;
    if (tid >= total) return;
    int b = tid / Pn;
    int p = tid - b * Pn;
    const int* ip = inds + (size_t)tid * 3;
    int m  = ip[0];
    int xi = ip[1];
    int yi = ip[2];
    if (m != 0) {
        atomicMax(&winner[(b * Hn + yi) * Wn + xi], p + 1);
    }
}

// Pass 2: streaming fill. Each thread owns 4 consecutive x positions of one
// (b,y) row and loops over all C channels, writing coalesced float4 stores.
// Zero cells write 0.0f; winner cells gather x[b,c,p] (12 MB, L2/L3-resident).
__global__ void pp_scatter_fill(const float* __restrict__ x,
                                const int* __restrict__ winner,
                                float* __restrict__ out) {
    int tid = blockIdx.x * blockDim.x + threadIdx.x;  // B*H*W/4 threads
    int b   = tid >> 16;          // H*W/4 = 65536 strips per batch
    int rem = tid & 65535;
    int y   = rem >> 7;           // W/4 = 128 strips per row
    int x4  = (rem & 127) << 2;

    const int4 w = *reinterpret_cast<const int4*>(&winner[(b * Hn + y) * Wn + x4]);
    const float* xb = x + (size_t)b * Cn * Pn;
    float* ob = out + (size_t)b * Cn * HWn + (size_t)y * Wn + x4;

#pragma unroll 4
    for (int c = 0; c < Cn; ++c) {
        float4 v;
        v.x = w.x ? xb[(size_t)c * Pn + (w.x - 1)] : 0.0f;
        v.y = w.y ? xb[(size_t)c * Pn + (w.y - 1)] : 0.0f;
        v.z = w.z ? xb[(size_t)c * Pn + (w.z - 1)] : 0.0f;
        v.w = w.w ? xb[(size_t)c * Pn + (w.w - 1)] : 0.0f;
        *reinterpret_cast<float4*>(&ob[(size_t)c * HWn]) = v;
    }
}

extern "C" void kernel_launch(void* const* d_in, const int* in_sizes, int n_in,
                              void* d_out, int out_size, void* d_ws, size_t ws_size,
                              hipStream_t stream) {
    const float* x    = (const float*)d_in[0];
    const int*   inds = (const int*)d_in[1];
    float* out    = (float*)d_out;
    int*   winner = (int*)d_ws;          // B*H*W ints = 4 MiB

    hipMemsetAsync(winner, 0, (size_t)Bn * Hn * Wn * sizeof(int), stream);

    int totalPts = Bn * Pn;
    pp_scatter_winner<<<(totalPts + 255) / 256, 256, 0, stream>>>(inds, winner, totalPts);

    int totalStrips = Bn * HWn / 4;      // 262144 threads
    pp_scatter_fill<<<totalStrips / 256, 256, 0, stream>>>(x, winner, out);
}